// Round 18
// baseline (28.232 us; speedup 1.0000x reference)
//
#include <hip/hip_runtime.h>
#include <hip/hip_bf16.h>

constexpr int NBATCH = 2048;   // B*T
constexpr int N      = 128;    // nodes
constexpr float INVTAU = 20.0f;   // 1/0.05
constexpr float EPSF   = 1e-8f;
constexpr float MUF    = 1.0f / 128.0f;   // mu = nu = 1/N
// K = expf(-20*sqrt(d2)) rounds to exactly 0.0f (even with denormal-
// preserving exp) iff 20*sqrt(d2) > 149*ln2 = 103.28, i.e. d2 > 26.66.
constexpr float D2_UNDERFLOW = 27.0f;

typedef __attribute__((ext_vector_type(8))) short short8;   // 8 x bf16 MFMA frag
typedef __attribute__((ext_vector_type(4))) float f32x4;    // MFMA accumulator
typedef __attribute__((ext_vector_type(2))) float f32x2;    // packed pair -> v_pk_fma_f32

static __device__ __forceinline__ float fastrcp(float x) {
    return __builtin_amdgcn_rcpf(x);    // v_rcp_f32, ~1e-7 rel err
}
static __device__ __forceinline__ float fastsqrt(float x) {
    return __builtin_amdgcn_sqrtf(x);   // raw v_sqrt_f32
}

// DPP cross-lane (VALU pipe, no DS op — r10: DS pipe was the bottleneck)
template <int CTRL>
static __device__ __forceinline__ float dpp_add(float s) {
    union { float f; int i; } a, b;
    a.f = s;
    b.i = __builtin_amdgcn_update_dpp(0, a.i, CTRL, 0xF, 0xF, false);
    return s + b.f;
}
template <int CTRL>
static __device__ __forceinline__ float dpp_min(float s) {
    union { float f; int i; } a, b;
    a.f = s;
    b.i = __builtin_amdgcn_update_dpp(0, a.i, CTRL, 0xF, 0xF, false);
    return fminf(s, b.f);
}
// all-reduce over a 16-lane row: row_ror 8,4,2,1
static __device__ __forceinline__ float row16_allreduce(float s) {
    s = dpp_add<0x128>(s);   // row_ror:8
    s = dpp_add<0x124>(s);   // row_ror:4
    s = dpp_add<0x122>(s);   // row_ror:2
    s = dpp_add<0x121>(s);   // row_ror:1
    return s;
}
static __device__ __forceinline__ float row16_minreduce(float s) {
    s = dpp_min<0x128>(s);
    s = dpp_min<0x124>(s);
    s = dpp_min<0x122>(s);
    s = dpp_min<0x121>(s);
    return s;
}
// all-reduce over an 8-lane group: quad_perm xor1, xor2, then half_mirror
static __device__ __forceinline__ float grp8_allreduce(float s) {
    s = dpp_add<0x0B1>(s);   // quad_perm [1,0,3,2]  (xor 1)
    s = dpp_add<0x04E>(s);   // quad_perm [2,3,0,1]  (xor 2)
    s = dpp_add<0x141>(s);   // row_half_mirror      (xor 7 within 8)
    return s;
}

// ROUND 18 = r17 shortcut, restructured for 4 blocks/CU (cap 64 VGPR).
// r17 is memory-path-bound: profiled 42us = 65.6MB FETCH at 1.56 TB/s with
// only 2 blocks/CU of outstanding loads. Fix: drop the dd2 array (32 regs)
// from the fast path — phase 1 folds d2 into dmin only; the (never-taken
// on this data) slow path RECOMPUTES d2 by re-running the MFMAs from the
// still-resident LDS staging (deterministic -> bit-identical to the voted
// values, so fast<->slow equivalence stays exact for any input). Register
// spills, if any, land in the never-executed slow region.
// Tripwire: WRITE_SIZE ~64 KB (fast-path spill would balloon it; fallback
// is (512,6)).
__global__ __launch_bounds__(512, 8)
void sinkhorn_batch(const float* __restrict__ srcg,
                    const float* __restrict__ tgtg,
                    float* __restrict__ lossg)
{
    // staging 32 KB; in the slow path it is overlaid by sPart AFTER the
    // phase-2 re-reads (extra barrier there)
    __shared__ ushort sStage[2 * N * 64];
    __shared__ float sX2[N], sY2[N];
    __shared__ float sVt[16 * 12];         // transposed v
    __shared__ float sRed[8];

    ushort* sA = sStage;
    ushort* sB = sStage + N * 64;
    float*  sPartF = reinterpret_cast<float*>(sStage);   // [col][36], 18 KB

    const int t  = threadIdx.x;
    const int l  = t & 63;
    const int w  = t >> 6;       // wave 0..7
    const int lx = l & 15;
    const int lh = l >> 4;       // 0..3
    const int bt = blockIdx.x;

    const float4* sg4 = reinterpret_cast<const float4*>(srcg + (size_t)bt * (N * 64));
    const float4* tg4 = reinterpret_cast<const float4*>(tgtg + (size_t)bt * (N * 64));

    // ---- phase 0: stage bf16 (swizzled, b128 stores) + norms via 8-lane DPP ----
    #pragma unroll
    for (int it = 0; it < 2; ++it) {
        int tp = t + 512 * it;         // 0..1023; 8 consecutive lanes = one row
        int r  = tp >> 3;
        int d8 = tp & 7;
        int f0 = tp * 2;
        float4 a0 = sg4[f0], a1 = sg4[f0 + 1];
        float4 b0 = tg4[f0], b1 = tg4[f0 + 1];
        float pa = a0.x * a0.x + a0.y * a0.y + a0.z * a0.z + a0.w * a0.w
                 + a1.x * a1.x + a1.y * a1.y + a1.z * a1.z + a1.w * a1.w;
        float pb = b0.x * b0.x + b0.y * b0.y + b0.z * b0.z + b0.w * b0.w
                 + b1.x * b1.x + b1.y * b1.y + b1.z * b1.z + b1.w * b1.w;
        pa = grp8_allreduce(pa);
        pb = grp8_allreduce(pb);
        if (d8 == 0) { sX2[r] = pa; sY2[r] = pb; }

        int idx = r * 64 + ((d8 ^ (r & 7)) << 3);   // b128 slot (16B aligned)
        union { __hip_bfloat162 h[4]; uint4 u; } ca, cb;
        ca.h[0] = __float22bfloat162_rn(make_float2(a0.x, a0.y));
        ca.h[1] = __float22bfloat162_rn(make_float2(a0.z, a0.w));
        ca.h[2] = __float22bfloat162_rn(make_float2(a1.x, a1.y));
        ca.h[3] = __float22bfloat162_rn(make_float2(a1.z, a1.w));
        cb.h[0] = __float22bfloat162_rn(make_float2(b0.x, b0.y));
        cb.h[1] = __float22bfloat162_rn(make_float2(b0.z, b0.w));
        cb.h[2] = __float22bfloat162_rn(make_float2(b1.x, b1.y));
        cb.h[3] = __float22bfloat162_rn(make_float2(b1.z, b1.w));
        *reinterpret_cast<uint4*>(&sA[idx]) = ca.u;
        *reinterpret_cast<uint4*>(&sB[idx]) = cb.u;
    }
    __syncthreads();

    // ---- phase 1: MFMA -> d2 folded into dmin ONLY (no dd2 array) ----
    float x2r[4], y2c[8];
    #pragma unroll
    for (int q = 0; q < 4; ++q) x2r[q] = sX2[16 * w + 4 * lh + q];
    #pragma unroll
    for (int tc = 0; tc < 8; ++tc) y2c[tc] = sY2[16 * tc + lx];

    short8 af0, af1;
    {
        int ra = 16 * w + lx;
        af0 = *reinterpret_cast<const short8*>(&sA[ra * 64 + (((0 + lh) ^ (ra & 7)) << 3)]);
        af1 = *reinterpret_cast<const short8*>(&sA[ra * 64 + (((4 + lh) ^ (ra & 7)) << 3)]);
    }

    float dmin = 1e30f;
    #pragma unroll
    for (int tc = 0; tc < 8; ++tc) {
        int rb = 16 * tc + lx;
        short8 bf0 = *reinterpret_cast<const short8*>(&sB[rb * 64 + (((0 + lh) ^ (rb & 7)) << 3)]);
        short8 bf1 = *reinterpret_cast<const short8*>(&sB[rb * 64 + (((4 + lh) ^ (rb & 7)) << 3)]);
        f32x4 acc = (f32x4){0.f, 0.f, 0.f, 0.f};
        acc = __builtin_amdgcn_mfma_f32_16x16x32_bf16(af0, bf0, acc, 0, 0, 0);
        acc = __builtin_amdgcn_mfma_f32_16x16x32_bf16(af1, bf1, acc, 0, 0, 0);
        #pragma unroll
        for (int q = 0; q < 4; ++q)
            dmin = fminf(dmin, fmaxf(x2r[q] + y2c[tc] - 2.0f * acc[q], 0.f));
    }

    // block-wide min vote
    dmin = row16_minreduce(dmin);
    dmin = fminf(dmin, __shfl_xor(dmin, 16));
    dmin = fminf(dmin, __shfl_xor(dmin, 32));
    if (l == 0) sRed[w] = dmin;
    if (t < N) sVt[(t & 15) * 12 + (t >> 4)] = 1.0f;   // v init (slow path)
    __syncthreads();

    float gmin = fminf(fminf(fminf(sRed[0], sRed[1]), fminf(sRed[2], sRed[3])),
                       fminf(fminf(sRed[4], sRed[5]), fminf(sRed[6], sRed[7])));
    if (gmin > D2_UNDERFLOW) {
        // every K == 0.0f exactly -> pi == 0 -> frame loss == 0 exactly
        if (t == 0) lossg[bt] = 0.0f;
        return;
    }

    // ================= slow path (block-uniform, rare) =================
    // Recompute d2 bit-identically from the still-resident staging, then
    // the r11 pipeline. Spills here are harmless (never executed above).
    f32x2 kk2[8][2];      // kk2[tc][p] = {K[q=2p], K[q=2p+1]}
    unsigned ccp[8][2];   // packed bf16 C
    #pragma unroll
    for (int tc = 0; tc < 8; ++tc) {
        int rb = 16 * tc + lx;
        short8 bf0 = *reinterpret_cast<const short8*>(&sB[rb * 64 + (((0 + lh) ^ (rb & 7)) << 3)]);
        short8 bf1 = *reinterpret_cast<const short8*>(&sB[rb * 64 + (((4 + lh) ^ (rb & 7)) << 3)]);
        f32x4 acc = (f32x4){0.f, 0.f, 0.f, 0.f};
        acc = __builtin_amdgcn_mfma_f32_16x16x32_bf16(af0, bf0, acc, 0, 0, 0);
        acc = __builtin_amdgcn_mfma_f32_16x16x32_bf16(af1, bf1, acc, 0, 0, 0);
        float cd[4];
        #pragma unroll
        for (int q = 0; q < 4; ++q)
            cd[q] = fastsqrt(fmaxf(x2r[q] + y2c[tc] - 2.0f * acc[q], 0.f));
        kk2[tc][0] = (f32x2){__expf(-INVTAU * cd[0]), __expf(-INVTAU * cd[1])};
        kk2[tc][1] = (f32x2){__expf(-INVTAU * cd[2]), __expf(-INVTAU * cd[3])};
        union { __hip_bfloat162 h; unsigned u; } p0, p1;
        p0.h = __float22bfloat162_rn(make_float2(cd[0], cd[1]));
        p1.h = __float22bfloat162_rn(make_float2(cd[2], cd[3]));
        ccp[tc][0] = p0.u;
        ccp[tc][1] = p1.u;
    }
    __syncthreads();   // staging re-reads done -> region becomes sPartF

    // ---- phase 3: Sinkhorn; u via DPP all-reduce, v via padded LDS partials ----
    f32x2 uu2[2];
    for (int iter = 0; iter < 5; ++iter) {
        f32x4 v03, v47;
        {
            const f32x4* pv = reinterpret_cast<const f32x4*>(&sVt[lx * 12]);
            v03 = pv[0];
            v47 = pv[1];
        }
        f32x2 p0 = (f32x2){0.f, 0.f}, p1 = (f32x2){0.f, 0.f};
        #pragma unroll
        for (int tc = 0; tc < 8; ++tc) {
            float vs = (tc < 4) ? v03[tc & 3] : v47[tc & 3];
            f32x2 vb = (f32x2){vs, vs};
            p0 = kk2[tc][0] * vb + p0;      // v_pk_fma_f32
            p1 = kk2[tc][1] * vb + p1;
        }
        float s0 = row16_allreduce(p0.x);
        float s1 = row16_allreduce(p0.y);
        float s2 = row16_allreduce(p1.x);
        float s3 = row16_allreduce(p1.y);
        uu2[0] = (f32x2){MUF * fastrcp(s0 + EPSF), MUF * fastrcp(s1 + EPSF)};
        uu2[1] = (f32x2){MUF * fastrcp(s2 + EPSF), MUF * fastrcp(s3 + EPSF)};

        #pragma unroll
        for (int tc = 0; tc < 8; ++tc) {
            f32x2 t2 = kk2[tc][0] * uu2[0] + kk2[tc][1] * uu2[1];
            sPartF[(tc * 16 + lx) * 36 + (w << 2) + lh] = t2.x + t2.y;
        }
        __syncthreads();
        if (t < N) {
            const f32x4* pr = reinterpret_cast<const f32x4*>(&sPartF[t * 36]);
            f32x4 a0 = pr[0], a1 = pr[1], a2 = pr[2], a3 = pr[3];
            f32x4 a4 = pr[4], a5 = pr[5], a6 = pr[6], a7 = pr[7];
            f32x4 ss = a0 + a1 + a2 + a3 + a4 + a5 + a6 + a7;
            float s = (ss[0] + ss[1]) + (ss[2] + ss[3]);
            sVt[(t & 15) * 12 + (t >> 4)] = MUF * fastrcp(s + EPSF);
        }
        __syncthreads();
    }

    // ---- phase 4: loss = sum u_i K_ij C_ij v_j ----
    f32x4 v03, v47;
    {
        const f32x4* pv = reinterpret_cast<const f32x4*>(&sVt[lx * 12]);
        v03 = pv[0];
        v47 = pv[1];
    }

    float part = 0.f;
    #pragma unroll
    for (int tc = 0; tc < 8; ++tc) {
        union { unsigned u; float f; } e0, e1, e2, e3;
        e0.u = ccp[tc][0] << 16;
        e1.u = ccp[tc][0] & 0xFFFF0000u;
        e2.u = ccp[tc][1] << 16;
        e3.u = ccp[tc][1] & 0xFFFF0000u;
        f32x2 c0 = (f32x2){e0.f, e1.f};
        f32x2 c1 = (f32x2){e2.f, e3.f};
        f32x2 r2 = uu2[0] * kk2[tc][0] * c0 + uu2[1] * kk2[tc][1] * c1;
        float vs = (tc < 4) ? v03[tc & 3] : v47[tc & 3];
        part += (r2.x + r2.y) * vs;
    }

    part = row16_allreduce(part);
    part += __shfl_xor(part, 16);
    part += __shfl_xor(part, 32);
    if (l == 0) sRed[w] = part;
    __syncthreads();
    if (t == 0) {
        float s = 0.f;
        #pragma unroll
        for (int i = 0; i < 8; ++i) s += sRed[i];
        lossg[bt] = s;
    }
}

// mean over 2048 per-frame losses -> d_out[0]
__global__ __launch_bounds__(256, 1)
void reduce_mean(const float* __restrict__ lossg, float* __restrict__ out)
{
    __shared__ float sRed[4];
    int t = threadIdx.x;
    float s = 0.f;
    #pragma unroll
    for (int it = 0; it < 8; ++it) s += lossg[t + 256 * it];
    #pragma unroll
    for (int off = 32; off >= 1; off >>= 1) s += __shfl_xor(s, off);
    if ((t & 63) == 0) sRed[t >> 6] = s;
    __syncthreads();
    if (t == 0) out[0] = (sRed[0] + sRed[1] + sRed[2] + sRed[3]) * (1.0f / 2048.0f);
}

extern "C" void kernel_launch(void* const* d_in, const int* in_sizes, int n_in,
                              void* d_out, int out_size, void* d_ws, size_t ws_size,
                              hipStream_t stream)
{
    const float* src = (const float*)d_in[0];
    const float* tgt = (const float*)d_in[1];
    float* ws = (float*)d_ws;                       // 2048 floats of scratch

    sinkhorn_batch<<<NBATCH, 512, 0, stream>>>(src, tgt, ws);
    reduce_mean<<<1, 256, 0, stream>>>(ws, (float*)d_out);
}

// Round 19
// 26.947 us; speedup vs baseline: 1.0477x; 1.0477x over previous
//
#include <hip/hip_runtime.h>
#include <hip/hip_bf16.h>

constexpr int NBATCH = 2048;   // B*T
constexpr int N      = 128;    // nodes
constexpr float INVTAU = 20.0f;   // 1/0.05
constexpr float EPSF   = 1e-8f;
constexpr float MUF    = 1.0f / 128.0f;   // mu = nu = 1/N
// K = expf(-20*sqrt(d2)) rounds to exactly 0.0f (even with denormal-
// preserving exp) iff 20*sqrt(d2) > 149*ln2 = 103.28, i.e. d2 > 26.66.
constexpr float D2_UNDERFLOW = 27.0f;

typedef __attribute__((ext_vector_type(8))) short short8;   // 8 x bf16 MFMA frag
typedef __attribute__((ext_vector_type(4))) float f32x4;    // MFMA accumulator
typedef __attribute__((ext_vector_type(2))) float f32x2;    // packed pair -> v_pk_fma_f32

static __device__ __forceinline__ float fastrcp(float x) {
    return __builtin_amdgcn_rcpf(x);    // v_rcp_f32, ~1e-7 rel err
}
static __device__ __forceinline__ float fastsqrt(float x) {
    return __builtin_amdgcn_sqrtf(x);   // raw v_sqrt_f32
}

// DPP cross-lane (VALU pipe, no DS op — r10: DS pipe was the bottleneck)
template <int CTRL>
static __device__ __forceinline__ float dpp_add(float s) {
    union { float f; int i; } a, b;
    a.f = s;
    b.i = __builtin_amdgcn_update_dpp(0, a.i, CTRL, 0xF, 0xF, false);
    return s + b.f;
}
template <int CTRL>
static __device__ __forceinline__ float dpp_min(float s) {
    union { float f; int i; } a, b;
    a.f = s;
    b.i = __builtin_amdgcn_update_dpp(0, a.i, CTRL, 0xF, 0xF, false);
    return fminf(s, b.f);
}
// all-reduce over a 16-lane row: row_ror 8,4,2,1
static __device__ __forceinline__ float row16_allreduce(float s) {
    s = dpp_add<0x128>(s);   // row_ror:8
    s = dpp_add<0x124>(s);   // row_ror:4
    s = dpp_add<0x122>(s);   // row_ror:2
    s = dpp_add<0x121>(s);   // row_ror:1
    return s;
}
static __device__ __forceinline__ float row16_minreduce(float s) {
    s = dpp_min<0x128>(s);
    s = dpp_min<0x124>(s);
    s = dpp_min<0x122>(s);
    s = dpp_min<0x121>(s);
    return s;
}
// all-reduce over an 8-lane group: quad_perm xor1, xor2, then half_mirror
static __device__ __forceinline__ float grp8_allreduce(float s) {
    s = dpp_add<0x0B1>(s);   // quad_perm [1,0,3,2]  (xor 1)
    s = dpp_add<0x04E>(s);   // quad_perm [2,3,0,1]  (xor 2)
    s = dpp_add<0x141>(s);   // row_half_mirror      (xor 7 within 8)
    return s;
}

// ROUND 19 = r18 with phase-0 restructured for wave-level MLP:
// issue ALL 8 global float4 loads back-to-back into distinct registers,
// THEN process (norms/convert/stage). r18's VGPR=32 suggests the compiler
// serialized load groups to reuse registers -> only ~4 loads in flight.
// bounds(512,6) (cap 85, 3 blocks/CU) gives the allocator headroom to keep
// all 8 live; r18 proved block count 2 vs 4 is perf-neutral, so 3 is safe.
// Slow path (never taken on this data, exact-vote-guarded) unchanged from
// r18: recomputes d2 bit-identically from staging. Tripwire: WRITE ~64 KB.
__global__ __launch_bounds__(512, 6)
void sinkhorn_batch(const float* __restrict__ srcg,
                    const float* __restrict__ tgtg,
                    float* __restrict__ lossg)
{
    __shared__ ushort sStage[2 * N * 64];
    __shared__ float sX2[N], sY2[N];
    __shared__ float sVt[16 * 12];         // transposed v
    __shared__ float sRed[8];

    ushort* sA = sStage;
    ushort* sB = sStage + N * 64;
    float*  sPartF = reinterpret_cast<float*>(sStage);   // [col][36], 18 KB

    const int t  = threadIdx.x;
    const int l  = t & 63;
    const int w  = t >> 6;       // wave 0..7
    const int lx = l & 15;
    const int lh = l >> 4;       // 0..3
    const int bt = blockIdx.x;

    const float4* sg4 = reinterpret_cast<const float4*>(srcg + (size_t)bt * (N * 64));
    const float4* tg4 = reinterpret_cast<const float4*>(tgtg + (size_t)bt * (N * 64));

    // ---- phase 0: ALL 8 loads first (max per-wave MLP), then process ----
    const int tp0 = t, tp1 = t + 512;
    float4 A0 = sg4[tp0 * 2], A1 = sg4[tp0 * 2 + 1];
    float4 B0 = tg4[tp0 * 2], B1 = tg4[tp0 * 2 + 1];
    float4 A2 = sg4[tp1 * 2], A3 = sg4[tp1 * 2 + 1];
    float4 B2 = tg4[tp1 * 2], B3 = tg4[tp1 * 2 + 1];

    #pragma unroll
    for (int it = 0; it < 2; ++it) {
        int tp = it ? tp1 : tp0;
        float4 a0 = it ? A2 : A0, a1 = it ? A3 : A1;
        float4 b0 = it ? B2 : B0, b1 = it ? B3 : B1;
        int r  = tp >> 3;
        int d8 = tp & 7;
        float pa = a0.x * a0.x + a0.y * a0.y + a0.z * a0.z + a0.w * a0.w
                 + a1.x * a1.x + a1.y * a1.y + a1.z * a1.z + a1.w * a1.w;
        float pb = b0.x * b0.x + b0.y * b0.y + b0.z * b0.z + b0.w * b0.w
                 + b1.x * b1.x + b1.y * b1.y + b1.z * b1.z + b1.w * b1.w;
        pa = grp8_allreduce(pa);
        pb = grp8_allreduce(pb);
        if (d8 == 0) { sX2[r] = pa; sY2[r] = pb; }

        int idx = r * 64 + ((d8 ^ (r & 7)) << 3);   // b128 slot (16B aligned)
        union { __hip_bfloat162 h[4]; uint4 u; } ca, cb;
        ca.h[0] = __float22bfloat162_rn(make_float2(a0.x, a0.y));
        ca.h[1] = __float22bfloat162_rn(make_float2(a0.z, a0.w));
        ca.h[2] = __float22bfloat162_rn(make_float2(a1.x, a1.y));
        ca.h[3] = __float22bfloat162_rn(make_float2(a1.z, a1.w));
        cb.h[0] = __float22bfloat162_rn(make_float2(b0.x, b0.y));
        cb.h[1] = __float22bfloat162_rn(make_float2(b0.z, b0.w));
        cb.h[2] = __float22bfloat162_rn(make_float2(b1.x, b1.y));
        cb.h[3] = __float22bfloat162_rn(make_float2(b1.z, b1.w));
        *reinterpret_cast<uint4*>(&sA[idx]) = ca.u;
        *reinterpret_cast<uint4*>(&sB[idx]) = cb.u;
    }
    __syncthreads();

    // ---- phase 1: MFMA -> d2 folded into dmin ONLY (no dd2 array) ----
    float x2r[4], y2c[8];
    #pragma unroll
    for (int q = 0; q < 4; ++q) x2r[q] = sX2[16 * w + 4 * lh + q];
    #pragma unroll
    for (int tc = 0; tc < 8; ++tc) y2c[tc] = sY2[16 * tc + lx];

    short8 af0, af1;
    {
        int ra = 16 * w + lx;
        af0 = *reinterpret_cast<const short8*>(&sA[ra * 64 + (((0 + lh) ^ (ra & 7)) << 3)]);
        af1 = *reinterpret_cast<const short8*>(&sA[ra * 64 + (((4 + lh) ^ (ra & 7)) << 3)]);
    }

    float dmin = 1e30f;
    #pragma unroll
    for (int tc = 0; tc < 8; ++tc) {
        int rb = 16 * tc + lx;
        short8 bf0 = *reinterpret_cast<const short8*>(&sB[rb * 64 + (((0 + lh) ^ (rb & 7)) << 3)]);
        short8 bf1 = *reinterpret_cast<const short8*>(&sB[rb * 64 + (((4 + lh) ^ (rb & 7)) << 3)]);
        f32x4 acc = (f32x4){0.f, 0.f, 0.f, 0.f};
        acc = __builtin_amdgcn_mfma_f32_16x16x32_bf16(af0, bf0, acc, 0, 0, 0);
        acc = __builtin_amdgcn_mfma_f32_16x16x32_bf16(af1, bf1, acc, 0, 0, 0);
        #pragma unroll
        for (int q = 0; q < 4; ++q)
            dmin = fminf(dmin, fmaxf(x2r[q] + y2c[tc] - 2.0f * acc[q], 0.f));
    }

    // block-wide min vote
    dmin = row16_minreduce(dmin);
    dmin = fminf(dmin, __shfl_xor(dmin, 16));
    dmin = fminf(dmin, __shfl_xor(dmin, 32));
    if (l == 0) sRed[w] = dmin;
    if (t < N) sVt[(t & 15) * 12 + (t >> 4)] = 1.0f;   // v init (slow path)
    __syncthreads();

    float gmin = fminf(fminf(fminf(sRed[0], sRed[1]), fminf(sRed[2], sRed[3])),
                       fminf(fminf(sRed[4], sRed[5]), fminf(sRed[6], sRed[7])));
    if (gmin > D2_UNDERFLOW) {
        // every K == 0.0f exactly -> pi == 0 -> frame loss == 0 exactly
        if (t == 0) lossg[bt] = 0.0f;
        return;
    }

    // ================= slow path (block-uniform, rare) =================
    // Recompute d2 bit-identically from the still-resident staging, then
    // the r11 pipeline. Spills here are harmless (never executed above).
    f32x2 kk2[8][2];      // kk2[tc][p] = {K[q=2p], K[q=2p+1]}
    unsigned ccp[8][2];   // packed bf16 C
    #pragma unroll
    for (int tc = 0; tc < 8; ++tc) {
        int rb = 16 * tc + lx;
        short8 bf0 = *reinterpret_cast<const short8*>(&sB[rb * 64 + (((0 + lh) ^ (rb & 7)) << 3)]);
        short8 bf1 = *reinterpret_cast<const short8*>(&sB[rb * 64 + (((4 + lh) ^ (rb & 7)) << 3)]);
        f32x4 acc = (f32x4){0.f, 0.f, 0.f, 0.f};
        acc = __builtin_amdgcn_mfma_f32_16x16x32_bf16(af0, bf0, acc, 0, 0, 0);
        acc = __builtin_amdgcn_mfma_f32_16x16x32_bf16(af1, bf1, acc, 0, 0, 0);
        float cd[4];
        #pragma unroll
        for (int q = 0; q < 4; ++q)
            cd[q] = fastsqrt(fmaxf(x2r[q] + y2c[tc] - 2.0f * acc[q], 0.f));
        kk2[tc][0] = (f32x2){__expf(-INVTAU * cd[0]), __expf(-INVTAU * cd[1])};
        kk2[tc][1] = (f32x2){__expf(-INVTAU * cd[2]), __expf(-INVTAU * cd[3])};
        union { __hip_bfloat162 h; unsigned u; } p0, p1;
        p0.h = __float22bfloat162_rn(make_float2(cd[0], cd[1]));
        p1.h = __float22bfloat162_rn(make_float2(cd[2], cd[3]));
        ccp[tc][0] = p0.u;
        ccp[tc][1] = p1.u;
    }
    __syncthreads();   // staging re-reads done -> region becomes sPartF

    // ---- phase 3: Sinkhorn; u via DPP all-reduce, v via padded LDS partials ----
    f32x2 uu2[2];
    for (int iter = 0; iter < 5; ++iter) {
        f32x4 v03, v47;
        {
            const f32x4* pv = reinterpret_cast<const f32x4*>(&sVt[lx * 12]);
            v03 = pv[0];
            v47 = pv[1];
        }
        f32x2 p0 = (f32x2){0.f, 0.f}, p1 = (f32x2){0.f, 0.f};
        #pragma unroll
        for (int tc = 0; tc < 8; ++tc) {
            float vs = (tc < 4) ? v03[tc & 3] : v47[tc & 3];
            f32x2 vb = (f32x2){vs, vs};
            p0 = kk2[tc][0] * vb + p0;      // v_pk_fma_f32
            p1 = kk2[tc][1] * vb + p1;
        }
        float s0 = row16_allreduce(p0.x);
        float s1 = row16_allreduce(p0.y);
        float s2 = row16_allreduce(p1.x);
        float s3 = row16_allreduce(p1.y);
        uu2[0] = (f32x2){MUF * fastrcp(s0 + EPSF), MUF * fastrcp(s1 + EPSF)};
        uu2[1] = (f32x2){MUF * fastrcp(s2 + EPSF), MUF * fastrcp(s3 + EPSF)};

        #pragma unroll
        for (int tc = 0; tc < 8; ++tc) {
            f32x2 t2 = kk2[tc][0] * uu2[0] + kk2[tc][1] * uu2[1];
            sPartF[(tc * 16 + lx) * 36 + (w << 2) + lh] = t2.x + t2.y;
        }
        __syncthreads();
        if (t < N) {
            const f32x4* pr = reinterpret_cast<const f32x4*>(&sPartF[t * 36]);
            f32x4 a0 = pr[0], a1 = pr[1], a2 = pr[2], a3 = pr[3];
            f32x4 a4 = pr[4], a5 = pr[5], a6 = pr[6], a7 = pr[7];
            f32x4 ss = a0 + a1 + a2 + a3 + a4 + a5 + a6 + a7;
            float s = (ss[0] + ss[1]) + (ss[2] + ss[3]);
            sVt[(t & 15) * 12 + (t >> 4)] = MUF * fastrcp(s + EPSF);
        }
        __syncthreads();
    }

    // ---- phase 4: loss = sum u_i K_ij C_ij v_j ----
    f32x4 v03, v47;
    {
        const f32x4* pv = reinterpret_cast<const f32x4*>(&sVt[lx * 12]);
        v03 = pv[0];
        v47 = pv[1];
    }

    float part = 0.f;
    #pragma unroll
    for (int tc = 0; tc < 8; ++tc) {
        union { unsigned u; float f; } e0, e1, e2, e3;
        e0.u = ccp[tc][0] << 16;
        e1.u = ccp[tc][0] & 0xFFFF0000u;
        e2.u = ccp[tc][1] << 16;
        e3.u = ccp[tc][1] & 0xFFFF0000u;
        f32x2 c0 = (f32x2){e0.f, e1.f};
        f32x2 c1 = (f32x2){e2.f, e3.f};
        f32x2 r2 = uu2[0] * kk2[tc][0] * c0 + uu2[1] * kk2[tc][1] * c1;
        float vs = (tc < 4) ? v03[tc & 3] : v47[tc & 3];
        part += (r2.x + r2.y) * vs;
    }

    part = row16_allreduce(part);
    part += __shfl_xor(part, 16);
    part += __shfl_xor(part, 32);
    if (l == 0) sRed[w] = part;
    __syncthreads();
    if (t == 0) {
        float s = 0.f;
        #pragma unroll
        for (int i = 0; i < 8; ++i) s += sRed[i];
        lossg[bt] = s;
    }
}

// mean over 2048 per-frame losses -> d_out[0]
__global__ __launch_bounds__(256, 1)
void reduce_mean(const float* __restrict__ lossg, float* __restrict__ out)
{
    __shared__ float sRed[4];
    int t = threadIdx.x;
    float s = 0.f;
    #pragma unroll
    for (int it = 0; it < 8; ++it) s += lossg[t + 256 * it];
    #pragma unroll
    for (int off = 32; off >= 1; off >>= 1) s += __shfl_xor(s, off);
    if ((t & 63) == 0) sRed[t >> 6] = s;
    __syncthreads();
    if (t == 0) out[0] = (sRed[0] + sRed[1] + sRed[2] + sRed[3]) * (1.0f / 2048.0f);
}

extern "C" void kernel_launch(void* const* d_in, const int* in_sizes, int n_in,
                              void* d_out, int out_size, void* d_ws, size_t ws_size,
                              hipStream_t stream)
{
    const float* src = (const float*)d_in[0];
    const float* tgt = (const float*)d_in[1];
    float* ws = (float*)d_ws;                       // 2048 floats of scratch

    sinkhorn_batch<<<NBATCH, 512, 0, stream>>>(src, tgt, ws);
    reduce_mean<<<1, 256, 0, stream>>>(ws, (float*)d_out);
}